// Round 6
// baseline (3507.340 us; speedup 1.0000x reference)
//
#include <hip/hip_runtime.h>
#include <stdint.h>

typedef __attribute__((ext_vector_type(8))) short short8;
typedef __attribute__((ext_vector_type(8))) unsigned short ushort8;
typedef __attribute__((ext_vector_type(4))) float floatx4;

#define BATCH 4096
#define HID   2048
#define KTOT  4096   // x-half (2048) then h-half (2048)

__device__ __forceinline__ uint16_t f2bf(float f) {
    union { uint32_t i; float f; } v; v.f = f;
    uint32_t u = v.i;
    u += 0x7fffu + ((u >> 16) & 1u);   // round-to-nearest-even
    return (uint16_t)(u >> 16);
}
__device__ __forceinline__ float sigmoid_f(float v) {
    return 1.0f / (1.0f + __expf(-v));
}
__device__ __forceinline__ float tanh_f(float v) {
    v = fminf(fmaxf(v, -15.0f), 15.0f);
    float e = __expf(-2.0f * v);
    return (1.0f - e) / (1.0f + e);
}
__device__ __forceinline__ void load_lds16(const uint16_t* g, uint16_t* l) {
    __builtin_amdgcn_global_load_lds(
        (const __attribute__((address_space(1))) void*)g,
        (__attribute__((address_space(3))) void*)l, 16, 0, 0);
}

// ===========================================================================
// Pre-pass 1: transpose+convert W (f32 K-major) -> wtf bf16 in MFMA-FRAGMENT
// order: chunk(g, w, kb) = 1 KB holding 64 lanes x 16 B, where lane l
// supplies col w*16+(l&15), k = kb*32+(l>>4)*8..+8. The GEMM then loads each
// B-fragment as ONE fully-coalesced global_load_dwordx4 at base + lane*16 --
// B never touches the GEMM's LDS.
// Flow: strided f32 reads -> reg 8x8 transpose -> LDS tile (stride 132 to
// spread readback banks; chunk-XOR on store) -> 1 KB-contiguous chunk writes.
// ===========================================================================
__global__ __launch_bounds__(256) void conv_w(
    const float* __restrict__ w0, const float* __restrict__ w1,
    const float* __restrict__ w2, const float* __restrict__ w3,
    const float* __restrict__ w4, const float* __restrict__ w5,
    const float* __restrict__ w6, const float* __restrict__ w7,
    uint16_t* __restrict__ wtf)
{
    __shared__ uint16_t tile[128 * 132];   // [n-row 0..127][k-chunk phys], stride 132

    int b   = blockIdx.x;
    int mi  = b >> 8;           // matrix index = gate*2 + half
    int rem = b & 255;
    int k0  = (rem >> 4) * 128; // k offset within the half
    int n0  = (rem & 15) * 128;
    const float* src;
    switch (mi) {
        case 0: src = w0; break; case 1: src = w1; break;
        case 2: src = w2; break; case 3: src = w3; break;
        case 4: src = w4; break; case 5: src = w5; break;
        case 6: src = w6; break; default: src = w7; break;
    }
    int g = mi >> 1, half = mi & 1;
    int t  = threadIdx.x;
    int ty = t >> 4, tx = t & 15;
    int kr = k0 + ty * 8;
    int nc = n0 + tx * 8;

    ushort8 a[8];
    #pragma unroll
    for (int j = 0; j < 8; ++j) {
        const float* s = src + (size_t)(kr + j) * HID + nc;
        floatx4 f0 = *(const floatx4*)(s);
        floatx4 f1 = *(const floatx4*)(s + 4);
        #pragma unroll
        for (int i = 0; i < 4; ++i) {
            a[j][i]     = f2bf(f0[i]);
            a[j][4 + i] = f2bf(f1[i]);
        }
    }
    ushort8 bt[8];
    #pragma unroll
    for (int i = 0; i < 8; ++i)
        #pragma unroll
        for (int j = 0; j < 8; ++j)
            bt[i][j] = a[j][i];

    // store: row r = tx*8+i (n-offset), logical k-chunk ty, phys = (ty^tx)&15
    #pragma unroll
    for (int i = 0; i < 8; ++i)
        *(ushort8*)(tile + (tx * 8 + i) * 132 + ((ty ^ tx) & 15) * 8) = bt[i];
    __syncthreads();

    // readback in fragment order: 32 chunks (8 w-windows x 4 kb), 8 thr each
    int ch  = t >> 3, sub = t & 7;
    int wl  = ch >> 2, kbl = ch & 3;
    int w   = (n0 >> 4) + wl;
    int kb  = half * 64 + (k0 >> 5) + kbl;
    size_t outbase = (((size_t)g * 128 + w) * 128 + kb) << 9;   // *512 elems
    #pragma unroll
    for (int j = 0; j < 8; ++j) {
        int l  = sub * 8 + j;
        int c  = l & 15, q = l >> 4;
        int r  = wl * 16 + c;
        int lc = kbl * 4 + q;
        int phys = (lc ^ (r >> 3)) & 15;
        ushort8 v = *(const ushort8*)(tile + r * 132 + phys * 8);
        *(ushort8*)(wtf + outbase + (size_t)l * 8) = v;
    }
}

// ===========================================================================
// Pre-pass 2: pack [x | h] f32 -> xh bf16 [4096][4096] row-major. (unchanged)
// ===========================================================================
__global__ __launch_bounds__(256) void conv_a(
    const float* __restrict__ x, const float* __restrict__ h,
    uint16_t* __restrict__ xh)
{
    size_t base = ((size_t)blockIdx.x * 256 + threadIdx.x) * 8;
    int m = (int)(base >> 12);
    int k = (int)(base & (KTOT - 1));
    const float* s = (k < HID) ? (x + (size_t)m * HID + k)
                               : (h + (size_t)m * HID + (k - HID));
    floatx4 f0 = *(const floatx4*)(s);
    floatx4 f1 = *(const floatx4*)(s + 4);
    ushort8 v;
    #pragma unroll
    for (int j = 0; j < 4; ++j) { v[j] = f2bf(f0[j]); v[4 + j] = f2bf(f1[j]); }
    *(ushort8*)(xh + base) = v;
}

// ===========================================================================
// GEMM v3: B-in-registers + A-only LDS dbuf + 2 blocks/CU + 1 barrier/K-tile.
// R4 post-mortem: 8-barrier phase lockstep at 1 block/CU serialized LDS
// (2300cy/K-tile) against MFMA (2483cy) -> 47% util. Fixes:
//  - B-frags load direct from wtf (fragment-order chunks, base + lane*16,
//    fully coalesced, L2-resident) into dbuf'd registers -> GEMM LDS traffic
//    drops to A only (1792cy < MFMA 2483cy).
//  - LDS = 2 x 32KB A tiles = 64KB -> 2 blocks/CU (4 waves/SIMD): cross-block
//    overlap replaces phase pacing; all intra-tile barriers removed.
//  - Per K-tile: issue A(t+1)+B(t+1) at tile START, one vmcnt(0)+s_barrier at
//    tile END -- every outstanding load is a full tile (~2300cy) old at the
//    drain -> zero stall, no fragile counting (compiler tracks B loads).
//  - launch_bounds(512,4): cap arch-VGPR at 128 (acc in AGPR file, ~105 VGPR
//    used: af 16 + bq 64 + addressing).
//  - XCD 2x4 rectangles kept (FETCH_SIZE 557->213MB measured in R4).
// ===========================================================================

#define DO_TILE(P, BQ_CUR, BQ_NXT, TN, DOST)                                  \
  {                                                                           \
    if (DOST) {                                                               \
      _Pragma("unroll") for (int p_ = 0; p_ < 4; ++p_)                        \
        load_lds16(gA + (size_t)p_ * (64 * KTOT) + (size_t)(TN) * 64,         \
                   lds + ((P) ^ 1) * 16384 + t * 8 + p_ * 4096);              \
      _Pragma("unroll") for (int g_ = 0; g_ < 4; ++g_)                        \
        _Pragma("unroll") for (int kh_ = 0; kh_ < 2; ++kh_)                   \
          BQ_NXT[g_][kh_] = *(const short8*)(gBfrag                           \
              + (size_t)g_ * 8388608 + (size_t)(TN) * 1024 + kh_ * 512);      \
    }                                                                         \
    _Pragma("unroll") for (int kh_ = 0; kh_ < 2; ++kh_) {                     \
      int pce = ((quad + kh_ * 4) ^ swz) * 8;                                 \
      short8 af[4];                                                           \
      _Pragma("unroll") for (int mi_ = 0; mi_ < 4; ++mi_)                     \
        af[mi_] = *(const short8*)(lds + (P) * 16384 + aRow * 64              \
                                   + mi_ * 1024 + pce);                       \
      __builtin_amdgcn_s_setprio(1);                                          \
      _Pragma("unroll") for (int mi_ = 0; mi_ < 4; ++mi_)                     \
        _Pragma("unroll") for (int g_ = 0; g_ < 4; ++g_)                      \
          acc[mi_][g_] = __builtin_amdgcn_mfma_f32_16x16x32_bf16(             \
              af[mi_], BQ_CUR[g_][kh_], acc[mi_][g_], 0, 0, 0);               \
      __builtin_amdgcn_s_setprio(0);                                          \
      _Pragma("unroll") for (int mi_ = 0; mi_ < 4; ++mi_)                     \
        af[mi_] = *(const short8*)(lds + (P) * 16384 + aRow * 64              \
                                   + (4 + mi_) * 1024 + pce);                 \
      __builtin_amdgcn_s_setprio(1);                                          \
      _Pragma("unroll") for (int mi_ = 0; mi_ < 4; ++mi_)                     \
        _Pragma("unroll") for (int g_ = 0; g_ < 4; ++g_)                      \
          acc[4 + mi_][g_] = __builtin_amdgcn_mfma_f32_16x16x32_bf16(         \
              af[mi_], BQ_CUR[g_][kh_], acc[4 + mi_][g_], 0, 0, 0);           \
      __builtin_amdgcn_s_setprio(0);                                          \
    }                                                                         \
    if (DOST) {                                                               \
      asm volatile("s_waitcnt vmcnt(0)" ::: "memory");                        \
      __builtin_amdgcn_s_barrier();                                           \
    }                                                                         \
  }

__global__ __launch_bounds__(512, 4) void lstm_gemm_bf16(
    const uint16_t* __restrict__ xh, const float* __restrict__ cx,
    const uint16_t* __restrict__ wtf,
    const float* __restrict__ bvi, const float* __restrict__ bvf,
    const float* __restrict__ bvo, const float* __restrict__ bvc,
    float* __restrict__ out)
{
    // A dbuf only: buf0 @ 0, buf1 @ 16384 (uint16 units) = 64 KiB total
    __shared__ uint16_t lds[32768];

    int t = threadIdx.x;

    // XCD remap: 512 blocks; XCD = linear&7 as 2x4 rectangles of 8my x 8nx
    int linear = blockIdx.x;
    int xcd = linear & 7;
    int idx = linear >> 3;                   // 0..63
    int my  = (xcd >> 2) * 8 + (idx >> 3);   // 0..15
    int nx  = (xcd & 3) * 8 + (idx & 7);     // 0..31
    int m0 = my * 256;
    int n0 = nx * 64;

    int wave = t >> 6, lane = t & 63;
    int wr = wave >> 2, wc = wave & 3;  // 2 M-halves x 4 gate-windows
    int lrow = lane & 15, quad = lane >> 4;
    int swz  = lrow & 7;

    // A staging: 512 thr x 16 B x 4 blocks covers 256 rows x 64 k
    int srow = t >> 3;                  // 0..63
    int schk = (t & 7) ^ (srow & 7);    // pre-swizzled global chunk
    const uint16_t* gA = xh + (size_t)(m0 + srow) * KTOT + (size_t)schk * 8;

    // B fragment base: chunk(g, w=nx*4+wc, kb) * 512 + lane*8
    const uint16_t* gBfrag = wtf + ((size_t)(nx * 4 + wc) << 16) + (size_t)lane * 8;

    // A fragment read base (chunk-XOR swizzled, unchanged from R4)
    int aRow = wr * 128 + lrow;

    floatx4 acc[8][4] = {};              // [mi][gate] -> AGPRs
    short8 bq0[4][2], bq1[4][2];         // B frags, [gate][kh], dbuf'd

    // prologue: A(0) -> buf0, B(0) -> bq0; drain (cold, ~1us total); sync
    #pragma unroll
    for (int p = 0; p < 4; ++p)
        load_lds16(gA + (size_t)p * (64 * KTOT), lds + t * 8 + p * 4096);
    #pragma unroll
    for (int g = 0; g < 4; ++g)
        #pragma unroll
        for (int kh = 0; kh < 2; ++kh)
            bq0[g][kh] = *(const short8*)(gBfrag + (size_t)g * 8388608 + kh * 512);
    asm volatile("s_waitcnt vmcnt(0)" ::: "memory");
    __builtin_amdgcn_s_barrier();

    // tiles 0..61 (issue t+1 at start; drain+barrier at end)
    for (int it = 0; it < 31; ++it) {
        DO_TILE(0, bq0, bq1, 2 * it + 1, 1);
        DO_TILE(1, bq1, bq0, 2 * it + 2, 1);
    }
    DO_TILE(0, bq0, bq1, 63, 1);   // t=62: issues A(63),B(63), syncs
    DO_TILE(1, bq1, bq0, 0, 0);    // t=63: pure compute, no sync

    // ---- fused LSTM epilogue (f32 in/out) ----
    int col = n0 + wc * 16 + lrow;
    float Bi = bvi[col], Bf = bvf[col], Bo = bvo[col], Bc = bvc[col];
    int rowb = m0 + wr * 128 + quad * 4;

    #pragma unroll
    for (int mi = 0; mi < 8; ++mi) {
        #pragma unroll
        for (int r = 0; r < 4; ++r) {
            int row = rowb + mi * 16 + r;
            size_t off = (size_t)row * HID + col;
            float gi = sigmoid_f(acc[mi][0][r] + Bi);
            float gf = sigmoid_f(acc[mi][1][r] + Bf);
            float go = sigmoid_f(acc[mi][2][r] + Bo);
            float gc = tanh_f   (acc[mi][3][r] + Bc);
            float cyv = gf * cx[off] + gi * gc;
            float hyv = go * tanh_f(cyv);
            out[off] = hyv;
            out[(size_t)BATCH * HID + off] = cyv;
        }
    }
}

// ===========================================================================
// Fallback (ws too small): proven fused kernel, f32 inputs. (unchanged)
// ===========================================================================
__global__ __launch_bounds__(256) void lstm_fused_f32(
    const float* __restrict__ x, const float* __restrict__ h,
    const float* __restrict__ cx,
    const float* __restrict__ wxi, const float* __restrict__ whi,
    const float* __restrict__ wxf, const float* __restrict__ whf,
    const float* __restrict__ wxo, const float* __restrict__ who,
    const float* __restrict__ wxc, const float* __restrict__ whc,
    const float* __restrict__ bvi, const float* __restrict__ bvf,
    const float* __restrict__ bvo, const float* __restrict__ bvc,
    float* __restrict__ out)
{
    __shared__ uint16_t ldsA[128 * 32];
    __shared__ uint16_t ldsB[128 * 32];
    uint32_t* ldsB32 = (uint32_t*)ldsB;

    int t    = threadIdx.x;
    int n0   = blockIdx.x * 32;
    int m0   = blockIdx.y * 128;
    int wave = t >> 6, lane = t & 63;
    int wr = wave >> 1, wc = wave & 1;
    int lrow = lane & 15, quad = lane >> 4;
    int srow = t >> 2;
    int sseg = (t & 3) * 8;
    int gw = wave;
    int ng = lane & 3;
    int ka = lane >> 2;
    const float *wxg, *whg;
    switch (gw) {
        case 0:  wxg = wxi; whg = whi; break;
        case 1:  wxg = wxf; whg = whf; break;
        case 2:  wxg = wxo; whg = who; break;
        default: wxg = wxc; whg = whc; break;
    }

    floatx4 acc[4][4] = {};

    for (int kt = 0; kt < KTOT / 32; ++kt) {
        int k0  = kt * 32;
        int k0h = k0 & (HID - 1);
        bool xhalf = (k0 < HID);

        ushort8 va[2];
        uint32_t bw[8];
        const float* a = xhalf ? x : h;
        #pragma unroll
        for (int p = 0; p < 2; ++p) {
            const float* s = a + (size_t)(m0 + srow + p * 64) * HID + k0h + sseg;
            floatx4 f0 = *(const floatx4*)(s);
            floatx4 f1 = *(const floatx4*)(s + 4);
            #pragma unroll
            for (int j = 0; j < 4; ++j) {
                va[p][j]     = (short)f2bf(f0[j]);
                va[p][4 + j] = (short)f2bf(f1[j]);
            }
        }
        const float* wp  = xhalf ? wxg : whg;
        const float* r0p = wp + (size_t)(k0h + 2 * ka) * HID + n0 + ng * 8;
        floatx4 a0 = *(const floatx4*)(r0p);
        floatx4 a1 = *(const floatx4*)(r0p + 4);
        floatx4 b0 = *(const floatx4*)(r0p + HID);
        floatx4 b1 = *(const floatx4*)(r0p + HID + 4);
        #pragma unroll
        for (int j = 0; j < 4; ++j) {
            bw[j]     = (uint32_t)f2bf(a0[j]) | ((uint32_t)f2bf(b0[j]) << 16);
            bw[4 + j] = (uint32_t)f2bf(a1[j]) | ((uint32_t)f2bf(b1[j]) << 16);
        }

        __syncthreads();
        #pragma unroll
        for (int p = 0; p < 2; ++p)
            *(ushort8*)(ldsA + (srow + p * 64) * 32 + sseg) = va[p];
        #pragma unroll
        for (int j = 0; j < 8; ++j)
            ldsB32[(gw * 32 + ng * 8 + j) * 16 + ka] = bw[j];
        __syncthreads();

        short8 af[4], bfr[4];
        #pragma unroll
        for (int mi = 0; mi < 4; ++mi)
            af[mi] = *(const short8*)(ldsA + (wr * 64 + mi * 16 + lrow) * 32 + quad * 8);
        #pragma unroll
        for (int g = 0; g < 4; ++g)
            bfr[g] = *(const short8*)(ldsB + (g * 32 + wc * 16 + lrow) * 32 + quad * 8);

        #pragma unroll
        for (int mi = 0; mi < 4; ++mi)
            #pragma unroll
            for (int g = 0; g < 4; ++g)
                acc[mi][g] = __builtin_amdgcn_mfma_f32_16x16x32_bf16(
                    af[mi], bfr[g], acc[mi][g], 0, 0, 0);
    }

    int col = n0 + wc * 16 + lrow;
    float Bi = bvi[col], Bf = bvf[col], Bo = bvo[col], Bc = bvc[col];
    int rowb = m0 + wr * 64 + quad * 4;

    #pragma unroll
    for (int mi = 0; mi < 4; ++mi) {
        #pragma unroll
        for (int r = 0; r < 4; ++r) {
            int row = rowb + mi * 16 + r;
            size_t off = (size_t)row * HID + col;
            float gi = sigmoid_f(acc[mi][0][r] + Bi);
            float gf = sigmoid_f(acc[mi][1][r] + Bf);
            float go = sigmoid_f(acc[mi][2][r] + Bo);
            float gc = tanh_f   (acc[mi][3][r] + Bc);
            float cyv = gf * cx[off] + gi * gc;
            float hyv = go * tanh_f(cyv);
            out[off] = hyv;
            out[(size_t)BATCH * HID + off] = cyv;
        }
    }
}

extern "C" void kernel_launch(void* const* d_in, const int* in_sizes, int n_in,
                              void* d_out, int out_size, void* d_ws, size_t ws_size,
                              hipStream_t stream) {
    const float* x    = (const float*)d_in[0];
    const float* h_x  = (const float*)d_in[1];
    const float* c_x  = (const float*)d_in[2];
    const float* W_xi = (const float*)d_in[3];
    const float* W_hi = (const float*)d_in[4];
    const float* b_i  = (const float*)d_in[5];
    const float* W_xf = (const float*)d_in[6];
    const float* W_hf = (const float*)d_in[7];
    const float* b_f  = (const float*)d_in[8];
    const float* W_xc = (const float*)d_in[9];
    const float* W_hc = (const float*)d_in[10];
    const float* b_c  = (const float*)d_in[11];
    const float* W_xo = (const float*)d_in[12];
    const float* W_ho = (const float*)d_in[13];
    const float* b_o  = (const float*)d_in[14];

    const size_t WT_BYTES = (size_t)4 * HID * KTOT * sizeof(uint16_t); // 64 MiB
    const size_t XH_BYTES = (size_t)BATCH * KTOT * sizeof(uint16_t);   // 32 MiB

    if (ws_size >= WT_BYTES + XH_BYTES) {
        uint16_t* wtf = (uint16_t*)d_ws;
        uint16_t* xh  = (uint16_t*)((char*)d_ws + WT_BYTES);
        // gate order i,f,o,c
        hipLaunchKernelGGL(conv_w, dim3(8 * 256), dim3(256), 0, stream,
                           W_xi, W_hi, W_xf, W_hf, W_xo, W_ho, W_xc, W_hc, wtf);
        hipLaunchKernelGGL(conv_a, dim3((BATCH * KTOT) / (256 * 8)), dim3(256), 0, stream,
                           x, h_x, xh);
        hipLaunchKernelGGL(lstm_gemm_bf16, dim3((BATCH / 256) * (HID / 64)), dim3(512), 0, stream,
                           xh, c_x, wtf, b_i, b_f, b_o, b_c, (float*)d_out);
    } else {
        hipLaunchKernelGGL(lstm_fused_f32, dim3(HID / 32, BATCH / 128), dim3(256), 0, stream,
                           x, h_x, c_x,
                           W_xi, W_hi, W_xf, W_hf, W_xo, W_ho, W_xc, W_hc,
                           b_i, b_f, b_o, b_c, (float*)d_out);
    }
}

// Round 8
// 546.536 us; speedup vs baseline: 6.4174x; 6.4174x over previous
//
#include <hip/hip_runtime.h>
#include <stdint.h>

typedef __attribute__((ext_vector_type(8))) short short8;
typedef __attribute__((ext_vector_type(8))) unsigned short ushort8;
typedef __attribute__((ext_vector_type(4))) float floatx4;

#define BATCH 4096
#define HID   2048
#define KTOT  4096   // x-half (2048) then h-half (2048)

__device__ __forceinline__ uint16_t f2bf(float f) {
    union { uint32_t i; float f; } v; v.f = f;
    uint32_t u = v.i;
    u += 0x7fffu + ((u >> 16) & 1u);   // round-to-nearest-even
    return (uint16_t)(u >> 16);
}
__device__ __forceinline__ float sigmoid_f(float v) {
    return 1.0f / (1.0f + __expf(-v));
}
__device__ __forceinline__ float tanh_f(float v) {
    v = fminf(fmaxf(v, -15.0f), 15.0f);
    float e = __expf(-2.0f * v);
    return (1.0f - e) / (1.0f + e);
}
__device__ __forceinline__ void load_lds16(const uint16_t* g, uint16_t* l) {
    __builtin_amdgcn_global_load_lds(
        (const __attribute__((address_space(1))) void*)g,
        (__attribute__((address_space(3))) void*)l, 16, 0, 0);
}

// ===========================================================================
// Pre-pass 1: transpose+convert W (f32 K-major) -> wtf bf16 in MFMA-FRAGMENT
// order: chunk(g, w, kb) = 1 KB holding 64 lanes x 16 B, where lane l
// supplies col w*16+(l&15), k = kb*32+(l>>4)*8..+8. (unchanged from R5/R6 —
// numerics verified by the passed R6 run)
// ===========================================================================
__global__ __launch_bounds__(256) void conv_w(
    const float* __restrict__ w0, const float* __restrict__ w1,
    const float* __restrict__ w2, const float* __restrict__ w3,
    const float* __restrict__ w4, const float* __restrict__ w5,
    const float* __restrict__ w6, const float* __restrict__ w7,
    uint16_t* __restrict__ wtf)
{
    __shared__ uint16_t tile[128 * 132];   // [n-row 0..127][k-chunk phys], stride 132

    int b   = blockIdx.x;
    int mi  = b >> 8;           // matrix index = gate*2 + half
    int rem = b & 255;
    int k0  = (rem >> 4) * 128; // k offset within the half
    int n0  = (rem & 15) * 128;
    const float* src;
    switch (mi) {
        case 0: src = w0; break; case 1: src = w1; break;
        case 2: src = w2; break; case 3: src = w3; break;
        case 4: src = w4; break; case 5: src = w5; break;
        case 6: src = w6; break; default: src = w7; break;
    }
    int g = mi >> 1, half = mi & 1;
    int t  = threadIdx.x;
    int ty = t >> 4, tx = t & 15;
    int kr = k0 + ty * 8;
    int nc = n0 + tx * 8;

    ushort8 a[8];
    #pragma unroll
    for (int j = 0; j < 8; ++j) {
        const float* s = src + (size_t)(kr + j) * HID + nc;
        floatx4 f0 = *(const floatx4*)(s);
        floatx4 f1 = *(const floatx4*)(s + 4);
        #pragma unroll
        for (int i = 0; i < 4; ++i) {
            a[j][i]     = f2bf(f0[i]);
            a[j][4 + i] = f2bf(f1[i]);
        }
    }
    ushort8 bt[8];
    #pragma unroll
    for (int i = 0; i < 8; ++i)
        #pragma unroll
        for (int j = 0; j < 8; ++j)
            bt[i][j] = a[j][i];

    // store: row r = tx*8+i (n-offset), logical k-chunk ty, phys = (ty^tx)&15
    #pragma unroll
    for (int i = 0; i < 8; ++i)
        *(ushort8*)(tile + (tx * 8 + i) * 132 + ((ty ^ tx) & 15) * 8) = bt[i];
    __syncthreads();

    // readback in fragment order: 32 chunks (8 w-windows x 4 kb), 8 thr each
    int ch  = t >> 3, sub = t & 7;
    int wl  = ch >> 2, kbl = ch & 3;
    int w   = (n0 >> 4) + wl;
    int kb  = half * 64 + (k0 >> 5) + kbl;
    size_t outbase = (((size_t)g * 128 + w) * 128 + kb) << 9;   // *512 elems
    #pragma unroll
    for (int j = 0; j < 8; ++j) {
        int l  = sub * 8 + j;
        int c  = l & 15, q = l >> 4;
        int r  = wl * 16 + c;
        int lc = kbl * 4 + q;
        int phys = (lc ^ (r >> 3)) & 15;
        ushort8 v = *(const ushort8*)(tile + r * 132 + phys * 8);
        *(ushort8*)(wtf + outbase + (size_t)l * 8) = v;
    }
}

// ===========================================================================
// Pre-pass 2: pack [x | h] f32 -> xh bf16 [4096][4096] row-major. (unchanged)
// ===========================================================================
__global__ __launch_bounds__(256) void conv_a(
    const float* __restrict__ x, const float* __restrict__ h,
    uint16_t* __restrict__ xh)
{
    size_t base = ((size_t)blockIdx.x * 256 + threadIdx.x) * 8;
    int m = (int)(base >> 12);
    int k = (int)(base & (KTOT - 1));
    const float* s = (k < HID) ? (x + (size_t)m * HID + k)
                               : (h + (size_t)m * HID + (k - HID));
    floatx4 f0 = *(const floatx4*)(s);
    floatx4 f1 = *(const floatx4*)(s + 4);
    ushort8 v;
    #pragma unroll
    for (int j = 0; j < 4; ++j) { v[j] = f2bf(f0[j]); v[4 + j] = f2bf(f1[j]); }
    *(ushort8*)(xh + base) = v;
}

// ===========================================================================
// GEMM v4: R6 concept with the REGISTER ARITHMETIC DONE.
// R6 spilled: launch_bounds(512,4) = 128-reg budget vs ~137 needed
// (VGPR_Count=64 clamp, 16 GB scratch traffic, MfmaUtil 3.5%). Changes:
//  - M-tile 256 -> 128: acc[4][4] = 16 AGPR (was 32); A dbuf = 32 KB LDS.
//  - B regs halved: bq0/bq1 hold one kh-half each (16+16 = 32 VGPR),
//    refilled IN PLACE: B(t)kh1 issues at tile start, B(t+1)kh0 issues
//    mid-tile after kh0's MFMAs -> every load >= ~600 cy ahead of use.
//  Budget: 32 bq + 16 af + ~25 addr + 16 acc ~= 90 <= 128. Margin real.
//  - 1024 blocks (32my x 32nx), 2 blocks/CU (4 waves/SIMD), 1 barrier+
//    vmcnt(0) per K-tile; everything drained is >=600 cy old -> free.
//  - B-frags direct from wtf (fragment-order, coalesced lane*16, L2-res).
//  - XCD rectangles: each XCD owns 8my x 16nx; idx sweeps nx inner so the
//    1 MB A-panel stays L2-hot across 16 consecutive blocks.
// ===========================================================================

#define DO_TILE(P, TN, STA, STB, SYNC)                                        \
  {                                                                           \
    if (STA) {                                                                \
      _Pragma("unroll") for (int p_ = 0; p_ < 2; ++p_)                        \
        load_lds16(gA + (size_t)p_ * (64 * KTOT) + (size_t)(TN + 1) * 64,     \
                   lds + ((P) ^ 1) * 8192 + p_ * 4096 + t * 8);               \
    }                                                                         \
    _Pragma("unroll") for (int g_ = 0; g_ < 4; ++g_)   /* B(t) kh1 */         \
      bq1[g_] = *(const short8*)(gBfrag + (size_t)g_ * 8388608                \
                                 + (size_t)(TN) * 1024 + 512);                \
    { /* kh0 compute, uses bq0 (issued mid-tile t-1) */                       \
      short8 af[4];                                                           \
      _Pragma("unroll") for (int mi_ = 0; mi_ < 4; ++mi_)                     \
        af[mi_] = *(const short8*)(lds + (P) * 8192                           \
                     + (aRow + mi_ * 16) * 64 + pc0e);                        \
      __builtin_amdgcn_s_setprio(1);                                          \
      _Pragma("unroll") for (int mi_ = 0; mi_ < 4; ++mi_)                     \
        _Pragma("unroll") for (int g_ = 0; g_ < 4; ++g_)                      \
          acc[mi_][g_] = __builtin_amdgcn_mfma_f32_16x16x32_bf16(             \
              af[mi_], bq0[g_], acc[mi_][g_], 0, 0, 0);                       \
      __builtin_amdgcn_s_setprio(0);                                          \
    }                                                                         \
    if (STB) {                                                                \
      _Pragma("unroll") for (int g_ = 0; g_ < 4; ++g_) /* B(t+1) kh0 */       \
        bq0[g_] = *(const short8*)(gBfrag + (size_t)g_ * 8388608              \
                                   + (size_t)(TN + 1) * 1024);                \
    }                                                                         \
    { /* kh1 compute, uses bq1 (issued at tile start) */                      \
      short8 af[4];                                                           \
      _Pragma("unroll") for (int mi_ = 0; mi_ < 4; ++mi_)                     \
        af[mi_] = *(const short8*)(lds + (P) * 8192                           \
                     + (aRow + mi_ * 16) * 64 + pc1e);                        \
      __builtin_amdgcn_s_setprio(1);                                          \
      _Pragma("unroll") for (int mi_ = 0; mi_ < 4; ++mi_)                     \
        _Pragma("unroll") for (int g_ = 0; g_ < 4; ++g_)                      \
          acc[mi_][g_] = __builtin_amdgcn_mfma_f32_16x16x32_bf16(             \
              af[mi_], bq1[g_], acc[mi_][g_], 0, 0, 0);                       \
      __builtin_amdgcn_s_setprio(0);                                          \
    }                                                                         \
    if (SYNC) {                                                               \
      asm volatile("s_waitcnt vmcnt(0)" ::: "memory");                        \
      __builtin_amdgcn_s_barrier();                                           \
    }                                                                         \
  }

__global__ __launch_bounds__(512, 4) void lstm_gemm_bf16(
    const uint16_t* __restrict__ xh, const float* __restrict__ cx,
    const uint16_t* __restrict__ wtf,
    const float* __restrict__ bvi, const float* __restrict__ bvf,
    const float* __restrict__ bvo, const float* __restrict__ bvc,
    float* __restrict__ out)
{
    // A dbuf only: buf0 @ 0, buf1 @ 8192 (uint16 units) = 32 KiB total
    __shared__ uint16_t lds[16384];

    int t = threadIdx.x;

    // XCD remap: 1024 blocks; XCD = linear&7 as 4x2 rectangles (8my x 16nx).
    // idx sweeps nx inner -> A panel (1 MB) L2-hot across 16 blocks.
    int linear = blockIdx.x;
    int xcd = linear & 7;
    int idx = linear >> 3;                   // 0..127
    int my  = (xcd >> 1) * 8 + (idx >> 4);   // 0..31
    int nx  = (xcd & 1) * 16 + (idx & 15);   // 0..31
    int m0 = my * 128;
    int n0 = nx * 64;

    int wave = t >> 6, lane = t & 63;
    int wr = wave >> 2, wc = wave & 3;  // 2 M-halves (64 rows) x 4 gate-wins
    int lrow = lane & 15, quad = lane >> 4;
    int swz  = lrow & 7;

    // A staging: 2 rounds x 512 thr x 16 B covers 128 rows x 64 k
    int srow = t >> 3;                  // 0..63 (round p adds 64)
    int schk = (t & 7) ^ (srow & 7);    // pre-swizzled global chunk
    const uint16_t* gA = xh + (size_t)(m0 + srow) * KTOT + (size_t)schk * 8;

    // B fragment base: chunk(g, w=nx*4+wc, kb) elems = g*8388608 + w*65536
    // + kb*512; per-lane +lane*8
    const uint16_t* gBfrag = wtf + ((size_t)(nx * 4 + wc) << 16) + (size_t)lane * 8;

    // A fragment read base (chunk-XOR swizzled)
    int aRow = wr * 64 + lrow;
    int pc0e = (quad ^ swz) * 8;         // kh0 logical chunk quad
    int pc1e = ((quad + 4) ^ swz) * 8;   // kh1 logical chunk quad+4

    floatx4 acc[4][4] = {};              // [mi][gate] -> 16 AGPR
    short8 bq0[4], bq1[4];               // one kh-half each, 16+16 VGPR

    // prologue: A(0) -> buf0 (2 loads), B(0)kh0 -> bq0; drain; sync
    #pragma unroll
    for (int p = 0; p < 2; ++p)
        load_lds16(gA + (size_t)p * (64 * KTOT), lds + p * 4096 + t * 8);
    #pragma unroll
    for (int g = 0; g < 4; ++g)
        bq0[g] = *(const short8*)(gBfrag + (size_t)g * 8388608);
    asm volatile("s_waitcnt vmcnt(0)" ::: "memory");
    __builtin_amdgcn_s_barrier();

    for (int it = 0; it < 31; ++it) {
        DO_TILE(0, 2 * it,     1, 1, 1);
        DO_TILE(1, 2 * it + 1, 1, 1, 1);
    }
    DO_TILE(0, 62, 1, 1, 1);   // stages A(63), issues B(63)kh0
    DO_TILE(1, 63, 0, 0, 0);   // pure compute (B(63)kh1 issued at its start)

    // ---- fused LSTM epilogue (f32 in/out) ----
    int col = n0 + wc * 16 + lrow;
    float Bi = bvi[col], Bf = bvf[col], Bo = bvo[col], Bc = bvc[col];
    int rowb = m0 + wr * 64 + quad * 4;

    #pragma unroll
    for (int mi = 0; mi < 4; ++mi) {
        #pragma unroll
        for (int r = 0; r < 4; ++r) {
            int row = rowb + mi * 16 + r;
            size_t off = (size_t)row * HID + col;
            float gi = sigmoid_f(acc[mi][0][r] + Bi);
            float gf = sigmoid_f(acc[mi][1][r] + Bf);
            float go = sigmoid_f(acc[mi][2][r] + Bo);
            float gc = tanh_f   (acc[mi][3][r] + Bc);
            float cyv = gf * cx[off] + gi * gc;
            float hyv = go * tanh_f(cyv);
            out[off] = hyv;
            out[(size_t)BATCH * HID + off] = cyv;
        }
    }
}

// ===========================================================================
// Fallback (ws too small): proven fused kernel, f32 inputs. (unchanged)
// ===========================================================================
__global__ __launch_bounds__(256) void lstm_fused_f32(
    const float* __restrict__ x, const float* __restrict__ h,
    const float* __restrict__ cx,
    const float* __restrict__ wxi, const float* __restrict__ whi,
    const float* __restrict__ wxf, const float* __restrict__ whf,
    const float* __restrict__ wxo, const float* __restrict__ who,
    const float* __restrict__ wxc, const float* __restrict__ whc,
    const float* __restrict__ bvi, const float* __restrict__ bvf,
    const float* __restrict__ bvo, const float* __restrict__ bvc,
    float* __restrict__ out)
{
    __shared__ uint16_t ldsA[128 * 32];
    __shared__ uint16_t ldsB[128 * 32];
    uint32_t* ldsB32 = (uint32_t*)ldsB;

    int t    = threadIdx.x;
    int n0   = blockIdx.x * 32;
    int m0   = blockIdx.y * 128;
    int wave = t >> 6, lane = t & 63;
    int wr = wave >> 1, wc = wave & 1;
    int lrow = lane & 15, quad = lane >> 4;
    int srow = t >> 2;
    int sseg = (t & 3) * 8;
    int gw = wave;
    int ng = lane & 3;
    int ka = lane >> 2;
    const float *wxg, *whg;
    switch (gw) {
        case 0:  wxg = wxi; whg = whi; break;
        case 1:  wxg = wxf; whg = whf; break;
        case 2:  wxg = wxo; whg = who; break;
        default: wxg = wxc; whg = whc; break;
    }

    floatx4 acc[4][4] = {};

    for (int kt = 0; kt < KTOT / 32; ++kt) {
        int k0  = kt * 32;
        int k0h = k0 & (HID - 1);
        bool xhalf = (k0 < HID);

        ushort8 va[2];
        uint32_t bw[8];
        const float* a = xhalf ? x : h;
        #pragma unroll
        for (int p = 0; p < 2; ++p) {
            const float* s = a + (size_t)(m0 + srow + p * 64) * HID + k0h + sseg;
            floatx4 f0 = *(const floatx4*)(s);
            floatx4 f1 = *(const floatx4*)(s + 4);
            #pragma unroll
            for (int j = 0; j < 4; ++j) {
                va[p][j]     = (short)f2bf(f0[j]);
                va[p][4 + j] = (short)f2bf(f1[j]);
            }
        }
        const float* wp  = xhalf ? wxg : whg;
        const float* r0p = wp + (size_t)(k0h + 2 * ka) * HID + n0 + ng * 8;
        floatx4 a0 = *(const floatx4*)(r0p);
        floatx4 a1 = *(const floatx4*)(r0p + 4);
        floatx4 b0 = *(const floatx4*)(r0p + HID);
        floatx4 b1 = *(const floatx4*)(r0p + HID + 4);
        #pragma unroll
        for (int j = 0; j < 4; ++j) {
            bw[j]     = (uint32_t)f2bf(a0[j]) | ((uint32_t)f2bf(b0[j]) << 16);
            bw[4 + j] = (uint32_t)f2bf(a1[j]) | ((uint32_t)f2bf(b1[j]) << 16);
        }

        __syncthreads();
        #pragma unroll
        for (int p = 0; p < 2; ++p)
            *(ushort8*)(ldsA + (srow + p * 64) * 32 + sseg) = va[p];
        #pragma unroll
        for (int j = 0; j < 8; ++j)
            ldsB32[(gw * 32 + ng * 8 + j) * 16 + ka] = bw[j];
        __syncthreads();

        short8 af[4], bfr[4];
        #pragma unroll
        for (int mi = 0; mi < 4; ++mi)
            af[mi] = *(const short8*)(ldsA + (wr * 64 + mi * 16 + lrow) * 32 + quad * 8);
        #pragma unroll
        for (int g = 0; g < 4; ++g)
            bfr[g] = *(const short8*)(ldsB + (g * 32 + wc * 16 + lrow) * 32 + quad * 8);

        #pragma unroll
        for (int mi = 0; mi < 4; ++mi)
            #pragma unroll
            for (int g = 0; g < 4; ++g)
                acc[mi][g] = __builtin_amdgcn_mfma_f32_16x16x32_bf16(
                    af[mi], bfr[g], acc[mi][g], 0, 0, 0);
    }

    int col = n0 + wc * 16 + lrow;
    float Bi = bvi[col], Bf = bvf[col], Bo = bvo[col], Bc = bvc[col];
    int rowb = m0 + wr * 64 + quad * 4;

    #pragma unroll
    for (int mi = 0; mi < 4; ++mi) {
        #pragma unroll
        for (int r = 0; r < 4; ++r) {
            int row = rowb + mi * 16 + r;
            size_t off = (size_t)row * HID + col;
            float gi = sigmoid_f(acc[mi][0][r] + Bi);
            float gf = sigmoid_f(acc[mi][1][r] + Bf);
            float go = sigmoid_f(acc[mi][2][r] + Bo);
            float gc = tanh_f   (acc[mi][3][r] + Bc);
            float cyv = gf * cx[off] + gi * gc;
            float hyv = go * tanh_f(cyv);
            out[off] = hyv;
            out[(size_t)BATCH * HID + off] = cyv;
        }
    }
}

extern "C" void kernel_launch(void* const* d_in, const int* in_sizes, int n_in,
                              void* d_out, int out_size, void* d_ws, size_t ws_size,
                              hipStream_t stream) {
    const float* x    = (const float*)d_in[0];
    const float* h_x  = (const float*)d_in[1];
    const float* c_x  = (const float*)d_in[2];
    const float* W_xi = (const float*)d_in[3];
    const float* W_hi = (const float*)d_in[4];
    const float* b_i  = (const float*)d_in[5];
    const float* W_xf = (const float*)d_in[6];
    const float* W_hf = (const float*)d_in[7];
    const float* b_f  = (const float*)d_in[8];
    const float* W_xc = (const float*)d_in[9];
    const float* W_hc = (const float*)d_in[10];
    const float* b_c  = (const float*)d_in[11];
    const float* W_xo = (const float*)d_in[12];
    const float* W_ho = (const float*)d_in[13];
    const float* b_o  = (const float*)d_in[14];

    const size_t WT_BYTES = (size_t)4 * HID * KTOT * sizeof(uint16_t); // 64 MiB
    const size_t XH_BYTES = (size_t)BATCH * KTOT * sizeof(uint16_t);   // 32 MiB

    if (ws_size >= WT_BYTES + XH_BYTES) {
        uint16_t* wtf = (uint16_t*)d_ws;
        uint16_t* xh  = (uint16_t*)((char*)d_ws + WT_BYTES);
        // gate order i,f,o,c
        hipLaunchKernelGGL(conv_w, dim3(8 * 256), dim3(256), 0, stream,
                           W_xi, W_hi, W_xf, W_hf, W_xo, W_ho, W_xc, W_hc, wtf);
        hipLaunchKernelGGL(conv_a, dim3((BATCH * KTOT) / (256 * 8)), dim3(256), 0, stream,
                           x, h_x, xh);
        hipLaunchKernelGGL(lstm_gemm_bf16, dim3((BATCH / 128) * (HID / 64)), dim3(512), 0, stream,
                           xh, c_x, wtf, b_i, b_f, b_o, b_c, (float*)d_out);
    } else {
        hipLaunchKernelGGL(lstm_fused_f32, dim3(HID / 32, BATCH / 128), dim3(256), 0, stream,
                           x, h_x, c_x,
                           W_xi, W_hi, W_xf, W_hf, W_xo, W_ho, W_xc, W_hc,
                           b_i, b_f, b_o, b_c, (float*)d_out);
    }
}

// Round 9
// 514.052 us; speedup vs baseline: 6.8229x; 1.0632x over previous
//
#include <hip/hip_runtime.h>
#include <stdint.h>

typedef __attribute__((ext_vector_type(8))) short short8;
typedef __attribute__((ext_vector_type(8))) unsigned short ushort8;
typedef __attribute__((ext_vector_type(4))) float floatx4;

#define BATCH 4096
#define HID   2048
#define KTOT  4096   // x-half (2048) then h-half (2048)

__device__ __forceinline__ uint16_t f2bf(float f) {
    union { uint32_t i; float f; } v; v.f = f;
    uint32_t u = v.i;
    u += 0x7fffu + ((u >> 16) & 1u);   // round-to-nearest-even
    return (uint16_t)(u >> 16);
}
__device__ __forceinline__ float sigmoid_f(float v) {
    return 1.0f / (1.0f + __expf(-v));
}
__device__ __forceinline__ float tanh_f(float v) {
    v = fminf(fmaxf(v, -15.0f), 15.0f);
    float e = __expf(-2.0f * v);
    return (1.0f - e) / (1.0f + e);
}
__device__ __forceinline__ void load_lds16(const uint16_t* g, uint16_t* l) {
    __builtin_amdgcn_global_load_lds(
        (const __attribute__((address_space(1))) void*)g,
        (__attribute__((address_space(3))) void*)l, 16, 0, 0);
}

// ===========================================================================
// MERGED pre-pass (one launch): blocks [0,1024) transpose W, [1024,2048)
// pack xh. Non-GEMM time has been ~211-242us every round vs ~45us ideal;
// this is the discriminating experiment (launch merge + streaming access).
//
// W-part: per block one 256n x 128k tile of one matrix (8 mats x 8 n x 16 k
// = 1024 blocks, 512 thr). Read: wave = 2 rows x 1KB contiguous. Register
// 8x8 transpose -> LDS [256][132] with chunk-XOR placement (bank math:
// 2-way worst = free). Write: 2 thr/row x 128B = 256B contiguous runs to
// wt [g][n][k4096] (same layout the R0 GEMM reads).
// A-part: thread packs 32 consecutive k (128B f32 read -> 64B bf16 write).
// ===========================================================================
__global__ __launch_bounds__(512) void conv_all(
    const float* __restrict__ w0, const float* __restrict__ w1,
    const float* __restrict__ w2, const float* __restrict__ w3,
    const float* __restrict__ w4, const float* __restrict__ w5,
    const float* __restrict__ w6, const float* __restrict__ w7,
    const float* __restrict__ x,  const float* __restrict__ h,
    uint16_t* __restrict__ wt,    uint16_t* __restrict__ xh)
{
    __shared__ uint16_t tile[256 * 132];   // 67.5 KB (W-part only)

    int t = threadIdx.x;

    if (blockIdx.x >= 1024) {
        // ---------------- A-part: pack [x | h] -> xh bf16 ----------------
        int idx = blockIdx.x - 1024;             // 0..1023
        int m   = idx * 4 + (t >> 7);            // 4 rows per block
        int k   = (t & 127) * 32;                // 32 consecutive k
        const float* s = (k < HID) ? (x + (size_t)m * HID + k)
                                   : (h + (size_t)m * HID + (k - HID));
        uint16_t* d = xh + (size_t)m * KTOT + k;
        #pragma unroll
        for (int q = 0; q < 4; ++q) {
            floatx4 f0 = *(const floatx4*)(s + q * 8);
            floatx4 f1 = *(const floatx4*)(s + q * 8 + 4);
            ushort8 v;
            #pragma unroll
            for (int j = 0; j < 4; ++j) { v[j] = f2bf(f0[j]); v[4+j] = f2bf(f1[j]); }
            *(ushort8*)(d + q * 8) = v;
        }
        return;
    }

    // ---------------- W-part: transpose+convert one 256n x 128k tile ------
    int b   = blockIdx.x;
    int mi  = b >> 7;            // matrix = gate*2 + half
    int rem = b & 127;
    int n0  = (rem >> 4) * 256;
    int k0  = (rem & 15) * 128;
    const float* src;
    switch (mi) {
        case 0: src = w0; break; case 1: src = w1; break;
        case 2: src = w2; break; case 3: src = w3; break;
        case 4: src = w4; break; case 5: src = w5; break;
        case 6: src = w6; break; default: src = w7; break;
    }
    int g = mi >> 1, half = mi & 1;

    // read 8x8 micro-tile: kg = t>>5 (k-group), ng = t&31 (n-group)
    // per j: lanes 0..31 of a wave cover one full 1KB row (contiguous).
    int kg = t >> 5, ng = t & 31;
    const float* rp = src + (size_t)(k0 + kg * 8) * HID + n0 + ng * 8;

    ushort8 a[8];
    #pragma unroll
    for (int j = 0; j < 8; ++j) {
        floatx4 f0 = *(const floatx4*)(rp + (size_t)j * HID);
        floatx4 f1 = *(const floatx4*)(rp + (size_t)j * HID + 4);
        #pragma unroll
        for (int i = 0; i < 4; ++i) {
            a[j][i]     = f2bf(f0[i]);
            a[j][4 + i] = f2bf(f1[i]);
        }
    }
    ushort8 bt[8];
    #pragma unroll
    for (int i = 0; i < 8; ++i)
        #pragma unroll
        for (int j = 0; j < 8; ++j)
            bt[i][j] = a[j][i];

    // LDS store: row n_local = ng*8+i, logical chunk kg, phys = kg^(ng&15)
    // bank spread: 16 distinct banks over ng 0..15 -> 2-way = free.
    #pragma unroll
    for (int i = 0; i < 8; ++i)
        *(ushort8*)(tile + (ng * 8 + i) * 132 + ((kg ^ ng) & 15) * 8) = bt[i];
    __syncthreads();

    // readback + store: 2 threads per n-row, 128 B each (contiguous 256 B/row)
    int nl = t >> 1, hf = t & 1;
    uint16_t* dst = wt + ((size_t)g * HID + n0 + nl) * KTOT
                       + (size_t)half * HID + k0 + hf * 64;
    int swr = (nl >> 3) & 15;
    #pragma unroll
    for (int j = 0; j < 8; ++j) {
        int c    = hf * 8 + j;                 // logical chunk 0..15
        int phys = (c ^ swr) & 15;
        ushort8 v = *(const ushort8*)(tile + nl * 132 + phys * 8);
        *(ushort8*)(dst + j * 8) = v;
    }
}

// ===========================================================================
// GEMM: REVERTED VERBATIM to the R0 baseline (proven 259us, MfmaUtil 50%,
// 3 blocks/CU). Three redesigns (R3 273, R4 265, R8 312) all lost to it.
// 128M x (4g x 32N) tile, BK=64, 256 thr, chunk-XOR LDS swizzle, width-16
// global_load_lds staging, fused f32 LSTM epilogue.
// ===========================================================================
__global__ __launch_bounds__(256, 4) void lstm_gemm_bf16(
    const uint16_t* __restrict__ xh, const float* __restrict__ cx,
    const uint16_t* __restrict__ wt,
    const float* __restrict__ bvi, const float* __restrict__ bvf,
    const float* __restrict__ bvo, const float* __restrict__ bvc,
    float* __restrict__ out)
{
    __shared__ uint16_t ldsA[128 * 64];   // 16 KB
    __shared__ uint16_t ldsB[128 * 64];   // 16 KB

    int t = threadIdx.x;
    // XCD-aware remap: a=linear&7 (XCD), b=(linear>>3)&3, c=linear>>5
    int linear = blockIdx.y * gridDim.x + blockIdx.x;   // 0..2047
    int my = (linear & 7) * 4 + ((linear >> 3) & 3);    // 0..31
    int nx = linear >> 5;                               // 0..63
    int n0 = nx * 32;
    int m0 = my * 128;

    int wave = t >> 6, lane = t & 63;
    int wr = wave >> 1, wc = wave & 1;
    int lrow = lane & 15, quad = lane >> 4;
    int swz  = lrow & 7;

    int srow = t >> 3;                     // staging row 0..31 (p adds 32)
    int schk = (t & 7) ^ (srow & 7);       // swizzled global chunk index

    floatx4 acc[4][4] = {};                // [mi][gate]

    for (int kt = 0; kt < KTOT / 64; ++kt) {
        int k0 = kt * 64;

        __syncthreads();   // previous iteration's fragment reads complete
        #pragma unroll
        for (int p = 0; p < 4; ++p) {      // A: 128 rows x 64 k
            int row = srow + p * 32;
            load_lds16(xh + (size_t)(m0 + row) * KTOT + k0 + schk * 8,
                       ldsA + p * 2048 + t * 8);
        }
        #pragma unroll
        for (int p = 0; p < 4; ++p) {      // B: 4 gates x 32 cols x 64 k
            int j = srow + p * 32;
            int g = j >> 5, dn = j & 31;
            load_lds16(wt + ((size_t)g * HID + n0 + dn) * KTOT + k0 + schk * 8,
                       ldsB + p * 2048 + t * 8);
        }
        __syncthreads();   // vmcnt drained at barrier -> tile visible

        #pragma unroll
        for (int kh = 0; kh < 2; ++kh) {
            int kkc = kh * 4;              // logical chunk base (k offset /8)
            short8 af[4], bfr[4];
            #pragma unroll
            for (int mi = 0; mi < 4; ++mi)
                af[mi] = *(const short8*)(ldsA + (wr * 64 + mi * 16 + lrow) * 64
                                               + (((quad + kkc) ^ swz)) * 8);
            #pragma unroll
            for (int g = 0; g < 4; ++g)
                bfr[g] = *(const short8*)(ldsB + (g * 32 + wc * 16 + lrow) * 64
                                               + (((quad + kkc) ^ swz)) * 8);
            #pragma unroll
            for (int mi = 0; mi < 4; ++mi)
                #pragma unroll
                for (int g = 0; g < 4; ++g)
                    acc[mi][g] = __builtin_amdgcn_mfma_f32_16x16x32_bf16(
                        af[mi], bfr[g], acc[mi][g], 0, 0, 0);
        }
    }

    // ---- fused LSTM epilogue (f32 in/out) ----
    int col = n0 + wc * 16 + lrow;
    float Bi = bvi[col], Bf = bvf[col], Bo = bvo[col], Bc = bvc[col];
    int rowb = m0 + wr * 64 + quad * 4;

    #pragma unroll
    for (int mi = 0; mi < 4; ++mi) {
        #pragma unroll
        for (int r = 0; r < 4; ++r) {
            int row = rowb + mi * 16 + r;
            size_t off = (size_t)row * HID + col;
            float gi = sigmoid_f(acc[mi][0][r] + Bi);
            float gf = sigmoid_f(acc[mi][1][r] + Bf);
            float go = sigmoid_f(acc[mi][2][r] + Bo);
            float gc = tanh_f   (acc[mi][3][r] + Bc);
            float cyv = gf * cx[off] + gi * gc;
            float hyv = go * tanh_f(cyv);
            out[off] = hyv;
            out[(size_t)BATCH * HID + off] = cyv;
        }
    }
}

// ===========================================================================
// Fallback (ws too small): proven fused kernel, f32 inputs. (unchanged)
// ===========================================================================
__global__ __launch_bounds__(256) void lstm_fused_f32(
    const float* __restrict__ x, const float* __restrict__ h,
    const float* __restrict__ cx,
    const float* __restrict__ wxi, const float* __restrict__ whi,
    const float* __restrict__ wxf, const float* __restrict__ whf,
    const float* __restrict__ wxo, const float* __restrict__ who,
    const float* __restrict__ wxc, const float* __restrict__ whc,
    const float* __restrict__ bvi, const float* __restrict__ bvf,
    const float* __restrict__ bvo, const float* __restrict__ bvc,
    float* __restrict__ out)
{
    __shared__ uint16_t ldsA[128 * 32];
    __shared__ uint16_t ldsB[128 * 32];
    uint32_t* ldsB32 = (uint32_t*)ldsB;

    int t    = threadIdx.x;
    int n0   = blockIdx.x * 32;
    int m0   = blockIdx.y * 128;
    int wave = t >> 6, lane = t & 63;
    int wr = wave >> 1, wc = wave & 1;
    int lrow = lane & 15, quad = lane >> 4;
    int srow = t >> 2;
    int sseg = (t & 3) * 8;
    int gw = wave;
    int ng = lane & 3;
    int ka = lane >> 2;
    const float *wxg, *whg;
    switch (gw) {
        case 0:  wxg = wxi; whg = whi; break;
        case 1:  wxg = wxf; whg = whf; break;
        case 2:  wxg = wxo; whg = who; break;
        default: wxg = wxc; whg = whc; break;
    }

    floatx4 acc[4][4] = {};

    for (int kt = 0; kt < KTOT / 32; ++kt) {
        int k0  = kt * 32;
        int k0h = k0 & (HID - 1);
        bool xhalf = (k0 < HID);

        ushort8 va[2];
        uint32_t bw[8];
        const float* a = xhalf ? x : h;
        #pragma unroll
        for (int p = 0; p < 2; ++p) {
            const float* s = a + (size_t)(m0 + srow + p * 64) * HID + k0h + sseg;
            floatx4 f0 = *(const floatx4*)(s);
            floatx4 f1 = *(const floatx4*)(s + 4);
            #pragma unroll
            for (int j = 0; j < 4; ++j) {
                va[p][j]     = (short)f2bf(f0[j]);
                va[p][4 + j] = (short)f2bf(f1[j]);
            }
        }
        const float* wp  = xhalf ? wxg : whg;
        const float* r0p = wp + (size_t)(k0h + 2 * ka) * HID + n0 + ng * 8;
        floatx4 a0 = *(const floatx4*)(r0p);
        floatx4 a1 = *(const floatx4*)(r0p + 4);
        floatx4 b0 = *(const floatx4*)(r0p + HID);
        floatx4 b1 = *(const floatx4*)(r0p + HID + 4);
        #pragma unroll
        for (int j = 0; j < 4; ++j) {
            bw[j]     = (uint32_t)f2bf(a0[j]) | ((uint32_t)f2bf(b0[j]) << 16);
            bw[4 + j] = (uint32_t)f2bf(a1[j]) | ((uint32_t)f2bf(b1[j]) << 16);
        }

        __syncthreads();
        #pragma unroll
        for (int p = 0; p < 2; ++p)
            *(ushort8*)(ldsA + (srow + p * 64) * 32 + sseg) = va[p];
        #pragma unroll
        for (int j = 0; j < 8; ++j)
            ldsB32[(gw * 32 + ng * 8 + j) * 16 + ka] = bw[j];
        __syncthreads();

        short8 af[4], bfr[4];
        #pragma unroll
        for (int mi = 0; mi < 4; ++mi)
            af[mi] = *(const short8*)(ldsA + (wr * 64 + mi * 16 + lrow) * 32 + quad * 8);
        #pragma unroll
        for (int g = 0; g < 4; ++g)
            bfr[g] = *(const short8*)(ldsB + (g * 32 + wc * 16 + lrow) * 32 + quad * 8);

        #pragma unroll
        for (int mi = 0; mi < 4; ++mi)
            #pragma unroll
            for (int g = 0; g < 4; ++g)
                acc[mi][g] = __builtin_amdgcn_mfma_f32_16x16x32_bf16(
                    af[mi], bfr[g], acc[mi][g], 0, 0, 0);
    }

    int col = n0 + wc * 16 + lrow;
    float Bi = bvi[col], Bf = bvf[col], Bo = bvo[col], Bc = bvc[col];
    int rowb = m0 + wr * 64 + quad * 4;

    #pragma unroll
    for (int mi = 0; mi < 4; ++mi) {
        #pragma unroll
        for (int r = 0; r < 4; ++r) {
            int row = rowb + mi * 16 + r;
            size_t off = (size_t)row * HID + col;
            float gi = sigmoid_f(acc[mi][0][r] + Bi);
            float gf = sigmoid_f(acc[mi][1][r] + Bf);
            float go = sigmoid_f(acc[mi][2][r] + Bo);
            float gc = tanh_f   (acc[mi][3][r] + Bc);
            float cyv = gf * cx[off] + gi * gc;
            float hyv = go * tanh_f(cyv);
            out[off] = hyv;
            out[(size_t)BATCH * HID + off] = cyv;
        }
    }
}

extern "C" void kernel_launch(void* const* d_in, const int* in_sizes, int n_in,
                              void* d_out, int out_size, void* d_ws, size_t ws_size,
                              hipStream_t stream) {
    const float* x    = (const float*)d_in[0];
    const float* h_x  = (const float*)d_in[1];
    const float* c_x  = (const float*)d_in[2];
    const float* W_xi = (const float*)d_in[3];
    const float* W_hi = (const float*)d_in[4];
    const float* b_i  = (const float*)d_in[5];
    const float* W_xf = (const float*)d_in[6];
    const float* W_hf = (const float*)d_in[7];
    const float* b_f  = (const float*)d_in[8];
    const float* W_xc = (const float*)d_in[9];
    const float* W_hc = (const float*)d_in[10];
    const float* b_c  = (const float*)d_in[11];
    const float* W_xo = (const float*)d_in[12];
    const float* W_ho = (const float*)d_in[13];
    const float* b_o  = (const float*)d_in[14];

    const size_t WT_BYTES = (size_t)4 * HID * KTOT * sizeof(uint16_t); // 64 MiB
    const size_t XH_BYTES = (size_t)BATCH * KTOT * sizeof(uint16_t);   // 32 MiB

    if (ws_size >= WT_BYTES + XH_BYTES) {
        uint16_t* wt = (uint16_t*)d_ws;
        uint16_t* xh = (uint16_t*)((char*)d_ws + WT_BYTES);
        // gate order i,f,o,c
        hipLaunchKernelGGL(conv_all, dim3(2048), dim3(512), 0, stream,
                           W_xi, W_hi, W_xf, W_hf, W_xo, W_ho, W_xc, W_hc,
                           x, h_x, wt, xh);
        hipLaunchKernelGGL(lstm_gemm_bf16, dim3(HID / 32, BATCH / 128), dim3(256), 0, stream,
                           xh, c_x, wt, b_i, b_f, b_o, b_c, (float*)d_out);
    } else {
        hipLaunchKernelGGL(lstm_fused_f32, dim3(HID / 32, BATCH / 128), dim3(256), 0, stream,
                           x, h_x, c_x,
                           W_xi, W_hi, W_xf, W_hf, W_xo, W_ho, W_xc, W_hc,
                           b_i, b_f, b_o, b_c, (float*)d_out);
    }
}

// Round 10
// 501.901 us; speedup vs baseline: 6.9881x; 1.0242x over previous
//
#include <hip/hip_runtime.h>
#include <stdint.h>

typedef __attribute__((ext_vector_type(8))) short short8;
typedef __attribute__((ext_vector_type(8))) unsigned short ushort8;
typedef __attribute__((ext_vector_type(4))) float floatx4;

#define BATCH 4096
#define HID   2048
#define KTOT  4096   // x-half (2048) then h-half (2048)

__device__ __forceinline__ uint16_t f2bf(float f) {
    union { uint32_t i; float f; } v; v.f = f;
    uint32_t u = v.i;
    u += 0x7fffu + ((u >> 16) & 1u);   // round-to-nearest-even
    return (uint16_t)(u >> 16);
}
__device__ __forceinline__ float sigmoid_f(float v) {
    return 1.0f / (1.0f + __expf(-v));
}
__device__ __forceinline__ float tanh_f(float v) {
    v = fminf(fmaxf(v, -15.0f), 15.0f);
    float e = __expf(-2.0f * v);
    return (1.0f - e) / (1.0f + e);
}
__device__ __forceinline__ void load_lds16(const uint16_t* g, uint16_t* l) {
    __builtin_amdgcn_global_load_lds(
        (const __attribute__((address_space(1))) void*)g,
        (__attribute__((address_space(3))) void*)l, 16, 0, 0);
}

// ===========================================================================
// Pre-pass 1: R4 conv_w VERBATIM (the fastest measured conv config:
// non-GEMM totalled 210us in R4 vs 242 R0 / 253 R9-merged).
// transpose+convert W (f32 K-major) -> wt bf16 [g][n][k4096] via register
// 8x8 transpose -> LDS 128x128 tile (chunk-XOR placement) -> 256 B
// contiguous global runs.
// ===========================================================================
__global__ __launch_bounds__(256) void conv_w(
    const float* __restrict__ w0, const float* __restrict__ w1,
    const float* __restrict__ w2, const float* __restrict__ w3,
    const float* __restrict__ w4, const float* __restrict__ w5,
    const float* __restrict__ w6, const float* __restrict__ w7,
    uint16_t* __restrict__ wt)
{
    __shared__ uint16_t tile[128 * 128];   // 32 KB: [n-row 0..127][k 0..127]

    int b   = blockIdx.x;
    int mi  = b >> 8;           // matrix index = gate*2 + half
    int rem = b & 255;
    int k0  = (rem >> 4) * 128;
    int n0  = (rem & 15) * 128;
    const float* src;
    switch (mi) {
        case 0: src = w0; break; case 1: src = w1; break;
        case 2: src = w2; break; case 3: src = w3; break;
        case 4: src = w4; break; case 5: src = w5; break;
        case 6: src = w6; break; default: src = w7; break;
    }
    int g = mi >> 1, half = mi & 1;
    int ty = threadIdx.x >> 4, tx = threadIdx.x & 15;
    int kr = k0 + ty * 8;
    int nc = n0 + tx * 8;

    ushort8 a[8];
    #pragma unroll
    for (int j = 0; j < 8; ++j) {
        const float* s = src + (size_t)(kr + j) * HID + nc;
        floatx4 f0 = *(const floatx4*)(s);
        floatx4 f1 = *(const floatx4*)(s + 4);
        #pragma unroll
        for (int i = 0; i < 4; ++i) {
            a[j][i]     = f2bf(f0[i]);
            a[j][4 + i] = f2bf(f1[i]);
        }
    }
    ushort8 bt[8];
    #pragma unroll
    for (int i = 0; i < 8; ++i)
        #pragma unroll
        for (int j = 0; j < 8; ++j)
            bt[i][j] = a[j][i];

    // LDS store: row = n-offset (tx*8+i), logical k-chunk = ty,
    // phys chunk = ty ^ (row>>3) = ty ^ tx.
    #pragma unroll
    for (int i = 0; i < 8; ++i)
        *(ushort8*)(tile + (tx * 8 + i) * 128 + ((ty ^ tx) & 15) * 8) = bt[i];
    __syncthreads();

    // Read back un-swizzled; 16 lanes x 16 B = 256 B contiguous per row.
    int t = threadIdx.x;
    #pragma unroll
    for (int p = 0; p < 8; ++p) {
        int r    = p * 16 + (t >> 4);          // n-row 0..127
        int lc   = t & 15;                     // logical k-chunk
        int phys = lc ^ ((r >> 3) & 15);
        ushort8 v = *(const ushort8*)(tile + r * 128 + phys * 8);
        *(ushort8*)(wt + ((size_t)g * HID + n0 + r) * KTOT
                       + half * HID + k0 + lc * 8) = v;
    }
}

// ===========================================================================
// Pre-pass 2: R4 conv_a VERBATIM. pack [x | h] f32 -> xh bf16 [4096][4096].
// 256 thr, no LDS -> 8 blocks/CU streaming.
// ===========================================================================
__global__ __launch_bounds__(256) void conv_a(
    const float* __restrict__ x, const float* __restrict__ h,
    uint16_t* __restrict__ xh)
{
    size_t base = ((size_t)blockIdx.x * 256 + threadIdx.x) * 8;
    int m = (int)(base >> 12);
    int k = (int)(base & (KTOT - 1));
    const float* s = (k < HID) ? (x + (size_t)m * HID + k)
                               : (h + (size_t)m * HID + (k - HID));
    floatx4 f0 = *(const floatx4*)(s);
    floatx4 f1 = *(const floatx4*)(s + 4);
    ushort8 v;
    #pragma unroll
    for (int j = 0; j < 4; ++j) { v[j] = f2bf(f0[j]); v[4 + j] = f2bf(f1[j]); }
    *(ushort8*)(xh + base) = v;
}

// ===========================================================================
// GEMM: R0 baseline VERBATIM (proven 259-262us, MfmaUtil 50-52%, 3 blk/CU).
// 128M x (4g x 32N) tile, BK=64, 256 thr, chunk-XOR LDS swizzle, width-16
// global_load_lds staging, fused f32 LSTM epilogue.
// ===========================================================================
__global__ __launch_bounds__(256, 4) void lstm_gemm_bf16(
    const uint16_t* __restrict__ xh, const float* __restrict__ cx,
    const uint16_t* __restrict__ wt,
    const float* __restrict__ bvi, const float* __restrict__ bvf,
    const float* __restrict__ bvo, const float* __restrict__ bvc,
    float* __restrict__ out)
{
    __shared__ uint16_t ldsA[128 * 64];   // 16 KB
    __shared__ uint16_t ldsB[128 * 64];   // 16 KB

    int t = threadIdx.x;
    // XCD-aware remap: a=linear&7 (XCD), b=(linear>>3)&3, c=linear>>5
    int linear = blockIdx.y * gridDim.x + blockIdx.x;   // 0..2047
    int my = (linear & 7) * 4 + ((linear >> 3) & 3);    // 0..31
    int nx = linear >> 5;                               // 0..63
    int n0 = nx * 32;
    int m0 = my * 128;

    int wave = t >> 6, lane = t & 63;
    int wr = wave >> 1, wc = wave & 1;
    int lrow = lane & 15, quad = lane >> 4;
    int swz  = lrow & 7;

    int srow = t >> 3;                     // staging row 0..31 (p adds 32)
    int schk = (t & 7) ^ (srow & 7);       // swizzled global chunk index

    floatx4 acc[4][4] = {};                // [mi][gate]

    for (int kt = 0; kt < KTOT / 64; ++kt) {
        int k0 = kt * 64;

        __syncthreads();   // previous iteration's fragment reads complete
        #pragma unroll
        for (int p = 0; p < 4; ++p) {      // A: 128 rows x 64 k
            int row = srow + p * 32;
            load_lds16(xh + (size_t)(m0 + row) * KTOT + k0 + schk * 8,
                       ldsA + p * 2048 + t * 8);
        }
        #pragma unroll
        for (int p = 0; p < 4; ++p) {      // B: 4 gates x 32 cols x 64 k
            int j = srow + p * 32;
            int g = j >> 5, dn = j & 31;
            load_lds16(wt + ((size_t)g * HID + n0 + dn) * KTOT + k0 + schk * 8,
                       ldsB + p * 2048 + t * 8);
        }
        __syncthreads();   // vmcnt drained at barrier -> tile visible

        #pragma unroll
        for (int kh = 0; kh < 2; ++kh) {
            int kkc = kh * 4;              // logical chunk base (k offset /8)
            short8 af[4], bfr[4];
            #pragma unroll
            for (int mi = 0; mi < 4; ++mi)
                af[mi] = *(const short8*)(ldsA + (wr * 64 + mi * 16 + lrow) * 64
                                               + (((quad + kkc) ^ swz)) * 8);
            #pragma unroll
            for (int g = 0; g < 4; ++g)
                bfr[g] = *(const short8*)(ldsB + (g * 32 + wc * 16 + lrow) * 64
                                               + (((quad + kkc) ^ swz)) * 8);
            #pragma unroll
            for (int mi = 0; mi < 4; ++mi)
                #pragma unroll
                for (int g = 0; g < 4; ++g)
                    acc[mi][g] = __builtin_amdgcn_mfma_f32_16x16x32_bf16(
                        af[mi], bfr[g], acc[mi][g], 0, 0, 0);
        }
    }

    // ---- fused LSTM epilogue (f32 in/out) ----
    int col = n0 + wc * 16 + lrow;
    float Bi = bvi[col], Bf = bvf[col], Bo = bvo[col], Bc = bvc[col];
    int rowb = m0 + wr * 64 + quad * 4;

    #pragma unroll
    for (int mi = 0; mi < 4; ++mi) {
        #pragma unroll
        for (int r = 0; r < 4; ++r) {
            int row = rowb + mi * 16 + r;
            size_t off = (size_t)row * HID + col;
            float gi = sigmoid_f(acc[mi][0][r] + Bi);
            float gf = sigmoid_f(acc[mi][1][r] + Bf);
            float go = sigmoid_f(acc[mi][2][r] + Bo);
            float gc = tanh_f   (acc[mi][3][r] + Bc);
            float cyv = gf * cx[off] + gi * gc;
            float hyv = go * tanh_f(cyv);
            out[off] = hyv;
            out[(size_t)BATCH * HID + off] = cyv;
        }
    }
}

// ===========================================================================
// Fallback (ws too small): proven fused kernel, f32 inputs. (unchanged)
// ===========================================================================
__global__ __launch_bounds__(256) void lstm_fused_f32(
    const float* __restrict__ x, const float* __restrict__ h,
    const float* __restrict__ cx,
    const float* __restrict__ wxi, const float* __restrict__ whi,
    const float* __restrict__ wxf, const float* __restrict__ whf,
    const float* __restrict__ wxo, const float* __restrict__ who,
    const float* __restrict__ wxc, const float* __restrict__ whc,
    const float* __restrict__ bvi, const float* __restrict__ bvf,
    const float* __restrict__ bvo, const float* __restrict__ bvc,
    float* __restrict__ out)
{
    __shared__ uint16_t ldsA[128 * 32];
    __shared__ uint16_t ldsB[128 * 32];
    uint32_t* ldsB32 = (uint32_t*)ldsB;

    int t    = threadIdx.x;
    int n0   = blockIdx.x * 32;
    int m0   = blockIdx.y * 128;
    int wave = t >> 6, lane = t & 63;
    int wr = wave >> 1, wc = wave & 1;
    int lrow = lane & 15, quad = lane >> 4;
    int srow = t >> 2;
    int sseg = (t & 3) * 8;
    int gw = wave;
    int ng = lane & 3;
    int ka = lane >> 2;
    const float *wxg, *whg;
    switch (gw) {
        case 0:  wxg = wxi; whg = whi; break;
        case 1:  wxg = wxf; whg = whf; break;
        case 2:  wxg = wxo; whg = who; break;
        default: wxg = wxc; whg = whc; break;
    }

    floatx4 acc[4][4] = {};

    for (int kt = 0; kt < KTOT / 32; ++kt) {
        int k0  = kt * 32;
        int k0h = k0 & (HID - 1);
        bool xhalf = (k0 < HID);

        ushort8 va[2];
        uint32_t bw[8];
        const float* a = xhalf ? x : h;
        #pragma unroll
        for (int p = 0; p < 2; ++p) {
            const float* s = a + (size_t)(m0 + srow + p * 64) * HID + k0h + sseg;
            floatx4 f0 = *(const floatx4*)(s);
            floatx4 f1 = *(const floatx4*)(s + 4);
            #pragma unroll
            for (int j = 0; j < 4; ++j) {
                va[p][j]     = (short)f2bf(f0[j]);
                va[p][4 + j] = (short)f2bf(f1[j]);
            }
        }
        const float* wp  = xhalf ? wxg : whg;
        const float* r0p = wp + (size_t)(k0h + 2 * ka) * HID + n0 + ng * 8;
        floatx4 a0 = *(const floatx4*)(r0p);
        floatx4 a1 = *(const floatx4*)(r0p + 4);
        floatx4 b0 = *(const floatx4*)(r0p + HID);
        floatx4 b1 = *(const floatx4*)(r0p + HID + 4);
        #pragma unroll
        for (int j = 0; j < 4; ++j) {
            bw[j]     = (uint32_t)f2bf(a0[j]) | ((uint32_t)f2bf(b0[j]) << 16);
            bw[4 + j] = (uint32_t)f2bf(a1[j]) | ((uint32_t)f2bf(b1[j]) << 16);
        }

        __syncthreads();
        #pragma unroll
        for (int p = 0; p < 2; ++p)
            *(ushort8*)(ldsA + (srow + p * 64) * 32 + sseg) = va[p];
        #pragma unroll
        for (int j = 0; j < 8; ++j)
            ldsB32[(gw * 32 + ng * 8 + j) * 16 + ka] = bw[j];
        __syncthreads();

        short8 af[4], bfr[4];
        #pragma unroll
        for (int mi = 0; mi < 4; ++mi)
            af[mi] = *(const short8*)(ldsA + (wr * 64 + mi * 16 + lrow) * 32 + quad * 8);
        #pragma unroll
        for (int g = 0; g < 4; ++g)
            bfr[g] = *(const short8*)(ldsB + (g * 32 + wc * 16 + lrow) * 32 + quad * 8);

        #pragma unroll
        for (int mi = 0; mi < 4; ++mi)
            #pragma unroll
            for (int g = 0; g < 4; ++g)
                acc[mi][g] = __builtin_amdgcn_mfma_f32_16x16x32_bf16(
                    af[mi], bfr[g], acc[mi][g], 0, 0, 0);
    }

    int col = n0 + wc * 16 + lrow;
    float Bi = bvi[col], Bf = bvf[col], Bo = bvo[col], Bc = bvc[col];
    int rowb = m0 + wr * 64 + quad * 4;

    #pragma unroll
    for (int mi = 0; mi < 4; ++mi) {
        #pragma unroll
        for (int r = 0; r < 4; ++r) {
            int row = rowb + mi * 16 + r;
            size_t off = (size_t)row * HID + col;
            float gi = sigmoid_f(acc[mi][0][r] + Bi);
            float gf = sigmoid_f(acc[mi][1][r] + Bf);
            float go = sigmoid_f(acc[mi][2][r] + Bo);
            float gc = tanh_f   (acc[mi][3][r] + Bc);
            float cyv = gf * cx[off] + gi * gc;
            float hyv = go * tanh_f(cyv);
            out[off] = hyv;
            out[(size_t)BATCH * HID + off] = cyv;
        }
    }
}

extern "C" void kernel_launch(void* const* d_in, const int* in_sizes, int n_in,
                              void* d_out, int out_size, void* d_ws, size_t ws_size,
                              hipStream_t stream) {
    const float* x    = (const float*)d_in[0];
    const float* h_x  = (const float*)d_in[1];
    const float* c_x  = (const float*)d_in[2];
    const float* W_xi = (const float*)d_in[3];
    const float* W_hi = (const float*)d_in[4];
    const float* b_i  = (const float*)d_in[5];
    const float* W_xf = (const float*)d_in[6];
    const float* W_hf = (const float*)d_in[7];
    const float* b_f  = (const float*)d_in[8];
    const float* W_xc = (const float*)d_in[9];
    const float* W_hc = (const float*)d_in[10];
    const float* b_c  = (const float*)d_in[11];
    const float* W_xo = (const float*)d_in[12];
    const float* W_ho = (const float*)d_in[13];
    const float* b_o  = (const float*)d_in[14];

    const size_t WT_BYTES = (size_t)4 * HID * KTOT * sizeof(uint16_t); // 64 MiB
    const size_t XH_BYTES = (size_t)BATCH * KTOT * sizeof(uint16_t);   // 32 MiB

    if (ws_size >= WT_BYTES + XH_BYTES) {
        uint16_t* wt = (uint16_t*)d_ws;
        uint16_t* xh = (uint16_t*)((char*)d_ws + WT_BYTES);
        // gate order i,f,o,c
        hipLaunchKernelGGL(conv_w, dim3(8 * 256), dim3(256), 0, stream,
                           W_xi, W_hi, W_xf, W_hf, W_xo, W_ho, W_xc, W_hc, wt);
        hipLaunchKernelGGL(conv_a, dim3((BATCH * KTOT) / (256 * 8)), dim3(256), 0, stream,
                           x, h_x, xh);
        hipLaunchKernelGGL(lstm_gemm_bf16, dim3(HID / 32, BATCH / 128), dim3(256), 0, stream,
                           xh, c_x, wt, b_i, b_f, b_o, b_c, (float*)d_out);
    } else {
        hipLaunchKernelGGL(lstm_fused_f32, dim3(HID / 32, BATCH / 128), dim3(256), 0, stream,
                           x, h_x, c_x,
                           W_xi, W_hi, W_xf, W_hf, W_xo, W_ho, W_xc, W_hc,
                           b_i, b_f, b_o, b_c, (float*)d_out);
    }
}

// Round 11
// 492.109 us; speedup vs baseline: 7.1272x; 1.0199x over previous
//
#include <hip/hip_runtime.h>
#include <stdint.h>

typedef __attribute__((ext_vector_type(8))) short short8;
typedef __attribute__((ext_vector_type(8))) unsigned short ushort8;
typedef __attribute__((ext_vector_type(4))) float floatx4;

#define BATCH 4096
#define HID   2048
#define KTOT  4096   // x-half (2048) then h-half (2048)

__device__ __forceinline__ uint16_t f2bf(float f) {
    union { uint32_t i; float f; } v; v.f = f;
    uint32_t u = v.i;
    u += 0x7fffu + ((u >> 16) & 1u);   // round-to-nearest-even
    return (uint16_t)(u >> 16);
}
__device__ __forceinline__ float sigmoid_f(float v) {
    return 1.0f / (1.0f + __expf(-v));
}
__device__ __forceinline__ float tanh_f(float v) {
    v = fminf(fmaxf(v, -15.0f), 15.0f);
    float e = __expf(-2.0f * v);
    return (1.0f - e) / (1.0f + e);
}
__device__ __forceinline__ void load_lds16(const uint16_t* g, uint16_t* l) {
    __builtin_amdgcn_global_load_lds(
        (const __attribute__((address_space(1))) void*)g,
        (__attribute__((address_space(3))) void*)l, 16, 0, 0);
}

// ===========================================================================
// Pre-pass 1: conv_w (R4/R10 verbatim — conv structure is exhausted as a
// lever; residual non-GEMM time is ~70us convs + fixed harness overhead).
// ===========================================================================
__global__ __launch_bounds__(256) void conv_w(
    const float* __restrict__ w0, const float* __restrict__ w1,
    const float* __restrict__ w2, const float* __restrict__ w3,
    const float* __restrict__ w4, const float* __restrict__ w5,
    const float* __restrict__ w6, const float* __restrict__ w7,
    uint16_t* __restrict__ wt)
{
    __shared__ uint16_t tile[128 * 128];   // 32 KB: [n-row 0..127][k 0..127]

    int b   = blockIdx.x;
    int mi  = b >> 8;           // matrix index = gate*2 + half
    int rem = b & 255;
    int k0  = (rem >> 4) * 128;
    int n0  = (rem & 15) * 128;
    const float* src;
    switch (mi) {
        case 0: src = w0; break; case 1: src = w1; break;
        case 2: src = w2; break; case 3: src = w3; break;
        case 4: src = w4; break; case 5: src = w5; break;
        case 6: src = w6; break; default: src = w7; break;
    }
    int g = mi >> 1, half = mi & 1;
    int ty = threadIdx.x >> 4, tx = threadIdx.x & 15;
    int kr = k0 + ty * 8;
    int nc = n0 + tx * 8;

    ushort8 a[8];
    #pragma unroll
    for (int j = 0; j < 8; ++j) {
        const float* s = src + (size_t)(kr + j) * HID + nc;
        floatx4 f0 = *(const floatx4*)(s);
        floatx4 f1 = *(const floatx4*)(s + 4);
        #pragma unroll
        for (int i = 0; i < 4; ++i) {
            a[j][i]     = f2bf(f0[i]);
            a[j][4 + i] = f2bf(f1[i]);
        }
    }
    ushort8 bt[8];
    #pragma unroll
    for (int i = 0; i < 8; ++i)
        #pragma unroll
        for (int j = 0; j < 8; ++j)
            bt[i][j] = a[j][i];

    #pragma unroll
    for (int i = 0; i < 8; ++i)
        *(ushort8*)(tile + (tx * 8 + i) * 128 + ((ty ^ tx) & 15) * 8) = bt[i];
    __syncthreads();

    int t = threadIdx.x;
    #pragma unroll
    for (int p = 0; p < 8; ++p) {
        int r    = p * 16 + (t >> 4);          // n-row 0..127
        int lc   = t & 15;                     // logical k-chunk
        int phys = lc ^ ((r >> 3) & 15);
        ushort8 v = *(const ushort8*)(tile + r * 128 + phys * 8);
        *(ushort8*)(wt + ((size_t)g * HID + n0 + r) * KTOT
                       + half * HID + k0 + lc * 8) = v;
    }
}

// ===========================================================================
// Pre-pass 2: conv_a (R4/R10 verbatim).
// ===========================================================================
__global__ __launch_bounds__(256) void conv_a(
    const float* __restrict__ x, const float* __restrict__ h,
    uint16_t* __restrict__ xh)
{
    size_t base = ((size_t)blockIdx.x * 256 + threadIdx.x) * 8;
    int m = (int)(base >> 12);
    int k = (int)(base & (KTOT - 1));
    const float* s = (k < HID) ? (x + (size_t)m * HID + k)
                               : (h + (size_t)m * HID + (k - HID));
    floatx4 f0 = *(const floatx4*)(s);
    floatx4 f1 = *(const floatx4*)(s + 4);
    ushort8 v;
    #pragma unroll
    for (int j = 0; j < 4; ++j) { v[j] = f2bf(f0[j]); v[4 + j] = f2bf(f1[j]); }
    *(ushort8*)(xh + base) = v;
}

// ===========================================================================
// GEMM v6: faithful m201 8-phase port (T3+T4+T5 on the proven T2 layout).
// 256M x (64n x 4gate) tile, BK=64, 512 thr / 8 waves (wr 2M x wc 4ncol),
// LDS 128 KiB = buf{0,1} x {A,B} x 256rows x 64k (proven 128-B-row
// chunk-XOR layout, 0 measured conflicts; regions = 128-row halves, 16 KB,
// naturally contiguous -> 2x global_load_lds each, 128-B staging runs).
//
// Ring ledger (iter computes T=2i in buf0 ph1-4, T+1 in buf1 ph5-8):
//   deaths: B.h* die at the phase their kh1 frags load (bf held in regs
//   across the mi4-7 phase); A.h* die at ph4/ph8.
//   stages: ph1:B1h1<-T+1  ph2:A1h0  ph3:A1h1  ph4:B0h0<-T+2  ph5:B0h1
//           ph6:A0h0  ph7:A0h1  ph8:B1h0<-T+3
//   every stage issues after the closing barrier of its region's last
//   reader -> race-free by barrier order.
//   vmcnt(2) at ph4-end and ph8-end (fixed point): each drains exactly the
//   4 regions needed next (loads 4-7 phases old -> zero-stall), leaves the
//   newest region in flight. NEVER vmcnt(0) in the main loop (m218 lever).
// Raw barriers + memory clobber + sched_barrier(0) (prevent ds_read hoist
// above the barrier publishing other waves' vmcnt); lgkmcnt(0)+sched_barrier
// before each MFMA cluster (rule 18); setprio(1) around MFMA (T5).
// Prologue: buf0 x4 + B1h0, vmcnt(2), barrier == steady entry state.
// Tail (it=31): ph1-3 stage <-63, ph4 vmcnt(0), ph5-8 no stage.
// ===========================================================================

#define BARRIER() do { asm volatile("" ::: "memory");                         \
                       __builtin_amdgcn_s_barrier();                          \
                       __builtin_amdgcn_sched_barrier(0); } while (0)
#define VM2 asm volatile("s_waitcnt vmcnt(2)" ::: "memory")
#define VM0 asm volatile("s_waitcnt vmcnt(0)" ::: "memory")

#define STAGE_A(BUF, H, KT) do {                                              \
    load_lds16(xh + (size_t)(m0 + (H)*128 + srow) * KTOT                      \
                   + (size_t)(KT)*64 + schk*8,                                \
               lds + (BUF)*32768 + (H)*8192 + t*8);                           \
    load_lds16(xh + (size_t)(m0 + (H)*128 + 64 + srow) * KTOT                 \
                   + (size_t)(KT)*64 + schk*8,                                \
               lds + (BUF)*32768 + (H)*8192 + 4096 + t*8);                    \
} while (0)

#define STAGE_B(BUF, H, KT) do {                                              \
    load_lds16(wt + ((size_t)((H)*2 + 0) * HID + n0 + srow) * KTOT            \
                   + (size_t)(KT)*64 + schk*8,                                \
               lds + (BUF)*32768 + 16384 + (H)*8192 + t*8);                   \
    load_lds16(wt + ((size_t)((H)*2 + 1) * HID + n0 + srow) * KTOT            \
                   + (size_t)(KT)*64 + schk*8,                                \
               lds + (BUF)*32768 + 16384 + (H)*8192 + 4096 + t*8);            \
} while (0)

#define PHASE(BUF, KH, MG, LDB, STAGES, VMW) do {                             \
    if (LDB) {                                                                \
      _Pragma("unroll") for (int g_ = 0; g_ < 4; ++g_)                        \
        bf[g_] = *(const short8*)(lds + (BUF)*32768 + 16384 + boff            \
                                  + g_*4096 + ((KH) ? pcx1 : pcx0));          \
    }                                                                         \
    _Pragma("unroll") for (int m_ = 0; m_ < 4; ++m_)                          \
      af[m_] = *(const short8*)(lds + (BUF)*32768 + aoff                      \
                                + ((MG)+m_)*1024 + ((KH) ? pcx1 : pcx0));     \
    STAGES                                                                    \
    BARRIER();                                                                \
    asm volatile("s_waitcnt lgkmcnt(0)" ::: "memory");                        \
    __builtin_amdgcn_sched_barrier(0);                                        \
    __builtin_amdgcn_s_setprio(1);                                            \
    _Pragma("unroll") for (int m_ = 0; m_ < 4; ++m_)                          \
      _Pragma("unroll") for (int g_ = 0; g_ < 4; ++g_)                        \
        acc[(MG)+m_][g_] = __builtin_amdgcn_mfma_f32_16x16x32_bf16(           \
            af[m_], bf[g_], acc[(MG)+m_][g_], 0, 0, 0);                       \
    __builtin_amdgcn_s_setprio(0);                                            \
    VMW                                                                       \
    BARRIER();                                                                \
} while (0)

__global__ __launch_bounds__(512, 2) void lstm_gemm_bf16(
    const uint16_t* __restrict__ xh, const float* __restrict__ cx,
    const uint16_t* __restrict__ wt,
    const float* __restrict__ bvi, const float* __restrict__ bvf,
    const float* __restrict__ bvo, const float* __restrict__ bvc,
    float* __restrict__ out)
{
    // A0 @0, B0 @16384, A1 @32768, B1 @49152 (uint16 units) = 128 KiB
    __shared__ uint16_t lds[65536];

    int t = threadIdx.x;

    // XCD remap (R4-measured: FETCH 557->213MB): 512 blocks, 2x4 rectangles
    // of 8my x 8nx per XCD.
    int linear = blockIdx.x;
    int xcd = linear & 7;
    int idx = linear >> 3;                   // 0..63
    int my  = (xcd >> 2) * 8 + (idx >> 3);   // 0..15
    int nx  = (xcd & 3) * 8 + (idx & 7);     // 0..31
    int m0 = my * 256;
    int n0 = nx * 64;

    int wave = t >> 6, lane = t & 63;
    int wr = wave >> 2, wc = wave & 3;       // 2 M-halves x 4 n-col windows
    int lrow = lane & 15, quad = lane >> 4;
    int swz  = lrow & 7;

    // staging: per region 2 loads x 512 thr x 16 B = 128 rows x 128 B
    int srow = t >> 3;                       // 0..63
    int schk = (t & 7) ^ (srow & 7);         // pre-swizzled global chunk

    // fragment bases (uint16 units)
    int aoff = (wr * 128 + lrow) * 64;
    int boff = (wc * 16 + lrow) * 64;
    int pcx0 = (quad ^ swz) * 8;             // kh0 chunk byte-pos
    int pcx1 = pcx0 ^ 32;                    // kh1 = chunk^4

    floatx4 acc[8][4] = {};                  // [mi][gate]
    short8 af[4], bf[4];

    // prologue: buf0 (tile 0) x4 regions + B1.h0 (tile 1); vmcnt(2) drains
    // buf0's 8, leaves B1.h0's 2 in flight == steady-state entry.
    STAGE_B(0, 0, 0);
    STAGE_B(0, 1, 0);
    STAGE_A(0, 0, 0);
    STAGE_A(0, 1, 0);
    STAGE_B(1, 0, 1);
    VM2;
    BARRIER();

    for (int it = 0; it < 32; ++it) {
        int k1 = 2 * it + 1;                 // tile T+1
        int k2 = 2 * it + 2;                 // tile T+2
        int k3 = 2 * it + 3;                 // tile T+3
        bool st = (it < 31);

        PHASE(0, 0, 0, 1, { STAGE_B(1, 1, k1); }, {});                  // ph1
        PHASE(0, 0, 4, 0, { STAGE_A(1, 0, k1); }, {});                  // ph2
        PHASE(0, 1, 0, 1, { STAGE_A(1, 1, k1); }, {});                  // ph3
        PHASE(0, 1, 4, 0, { if (st) STAGE_B(0, 0, k2); },
                          { if (st) { VM2; } else { VM0; } });          // ph4
        PHASE(1, 0, 0, 1, { if (st) STAGE_B(0, 1, k2); }, {});          // ph5
        PHASE(1, 0, 4, 0, { if (st) STAGE_A(0, 0, k2); }, {});          // ph6
        PHASE(1, 1, 0, 1, { if (st) STAGE_A(0, 1, k2); }, {});          // ph7
        PHASE(1, 1, 4, 0, { if (st) STAGE_B(1, 0, k3); },
                          { if (st) { VM2; } });                        // ph8
    }

    // ---- fused LSTM epilogue (f32 in/out) ----
    int col = n0 + wc * 16 + lrow;
    float Bi = bvi[col], Bf = bvf[col], Bo = bvo[col], Bc = bvc[col];
    int rowb = m0 + wr * 128 + quad * 4;

    #pragma unroll
    for (int mi = 0; mi < 8; ++mi) {
        #pragma unroll
        for (int r = 0; r < 4; ++r) {
            int row = rowb + mi * 16 + r;
            size_t off = (size_t)row * HID + col;
            float gi = sigmoid_f(acc[mi][0][r] + Bi);
            float gf = sigmoid_f(acc[mi][1][r] + Bf);
            float go = sigmoid_f(acc[mi][2][r] + Bo);
            float gc = tanh_f   (acc[mi][3][r] + Bc);
            float cyv = gf * cx[off] + gi * gc;
            float hyv = go * tanh_f(cyv);
            out[off] = hyv;
            out[(size_t)BATCH * HID + off] = cyv;
        }
    }
}

// ===========================================================================
// Fallback (ws too small): proven fused kernel, f32 inputs. (unchanged)
// ===========================================================================
__global__ __launch_bounds__(256) void lstm_fused_f32(
    const float* __restrict__ x, const float* __restrict__ h,
    const float* __restrict__ cx,
    const float* __restrict__ wxi, const float* __restrict__ whi,
    const float* __restrict__ wxf, const float* __restrict__ whf,
    const float* __restrict__ wxo, const float* __restrict__ who,
    const float* __restrict__ wxc, const float* __restrict__ whc,
    const float* __restrict__ bvi, const float* __restrict__ bvf,
    const float* __restrict__ bvo, const float* __restrict__ bvc,
    float* __restrict__ out)
{
    __shared__ uint16_t ldsA[128 * 32];
    __shared__ uint16_t ldsB[128 * 32];
    uint32_t* ldsB32 = (uint32_t*)ldsB;

    int t    = threadIdx.x;
    int n0   = blockIdx.x * 32;
    int m0   = blockIdx.y * 128;
    int wave = t >> 6, lane = t & 63;
    int wr = wave >> 1, wc = wave & 1;
    int lrow = lane & 15, quad = lane >> 4;
    int srow = t >> 2;
    int sseg = (t & 3) * 8;
    int gw = wave;
    int ng = lane & 3;
    int ka = lane >> 2;
    const float *wxg, *whg;
    switch (gw) {
        case 0:  wxg = wxi; whg = whi; break;
        case 1:  wxg = wxf; whg = whf; break;
        case 2:  wxg = wxo; whg = who; break;
        default: wxg = wxc; whg = whc; break;
    }

    floatx4 acc[4][4] = {};

    for (int kt = 0; kt < KTOT / 32; ++kt) {
        int k0  = kt * 32;
        int k0h = k0 & (HID - 1);
        bool xhalf = (k0 < HID);

        ushort8 va[2];
        uint32_t bw[8];
        const float* a = xhalf ? x : h;
        #pragma unroll
        for (int p = 0; p < 2; ++p) {
            const float* s = a + (size_t)(m0 + srow + p * 64) * HID + k0h + sseg;
            floatx4 f0 = *(const floatx4*)(s);
            floatx4 f1 = *(const floatx4*)(s + 4);
            #pragma unroll
            for (int j = 0; j < 4; ++j) {
                va[p][j]     = (short)f2bf(f0[j]);
                va[p][4 + j] = (short)f2bf(f1[j]);
            }
        }
        const float* wp  = xhalf ? wxg : whg;
        const float* r0p = wp + (size_t)(k0h + 2 * ka) * HID + n0 + ng * 8;
        floatx4 a0 = *(const floatx4*)(r0p);
        floatx4 a1 = *(const floatx4*)(r0p + 4);
        floatx4 b0 = *(const floatx4*)(r0p + HID);
        floatx4 b1 = *(const floatx4*)(r0p + HID + 4);
        #pragma unroll
        for (int j = 0; j < 4; ++j) {
            bw[j]     = (uint32_t)f2bf(a0[j]) | ((uint32_t)f2bf(b0[j]) << 16);
            bw[4 + j] = (uint32_t)f2bf(a1[j]) | ((uint32_t)f2bf(b1[j]) << 16);
        }

        __syncthreads();
        #pragma unroll
        for (int p = 0; p < 2; ++p)
            *(ushort8*)(ldsA + (srow + p * 64) * 32 + sseg) = va[p];
        #pragma unroll
        for (int j = 0; j < 8; ++j)
            ldsB32[(gw * 32 + ng * 8 + j) * 16 + ka] = bw[j];
        __syncthreads();

        short8 af[4], bfr[4];
        #pragma unroll
        for (int mi = 0; mi < 4; ++mi)
            af[mi] = *(const short8*)(ldsA + (wr * 64 + mi * 16 + lrow) * 32 + quad * 8);
        #pragma unroll
        for (int g = 0; g < 4; ++g)
            bfr[g] = *(const short8*)(ldsB + (g * 32 + wc * 16 + lrow) * 32 + quad * 8);

        #pragma unroll
        for (int mi = 0; mi < 4; ++mi)
            #pragma unroll
            for (int g = 0; g < 4; ++g)
                acc[mi][g] = __builtin_amdgcn_mfma_f32_16x16x32_bf16(
                    af[mi], bfr[g], acc[mi][g], 0, 0, 0);
    }

    int col = n0 + wc * 16 + lrow;
    float Bi = bvi[col], Bf = bvf[col], Bo = bvo[col], Bc = bvc[col];
    int rowb = m0 + wr * 64 + quad * 4;

    #pragma unroll
    for (int mi = 0; mi < 4; ++mi) {
        #pragma unroll
        for (int r = 0; r < 4; ++r) {
            int row = rowb + mi * 16 + r;
            size_t off = (size_t)row * HID + col;
            float gi = sigmoid_f(acc[mi][0][r] + Bi);
            float gf = sigmoid_f(acc[mi][1][r] + Bf);
            float go = sigmoid_f(acc[mi][2][r] + Bo);
            float gc = tanh_f   (acc[mi][3][r] + Bc);
            float cyv = gf * cx[off] + gi * gc;
            float hyv = go * tanh_f(cyv);
            out[off] = hyv;
            out[(size_t)BATCH * HID + off] = cyv;
        }
    }
}

extern "C" void kernel_launch(void* const* d_in, const int* in_sizes, int n_in,
                              void* d_out, int out_size, void* d_ws, size_t ws_size,
                              hipStream_t stream) {
    const float* x    = (const float*)d_in[0];
    const float* h_x  = (const float*)d_in[1];
    const float* c_x  = (const float*)d_in[2];
    const float* W_xi = (const float*)d_in[3];
    const float* W_hi = (const float*)d_in[4];
    const float* b_i  = (const float*)d_in[5];
    const float* W_xf = (const float*)d_in[6];
    const float* W_hf = (const float*)d_in[7];
    const float* b_f  = (const float*)d_in[8];
    const float* W_xc = (const float*)d_in[9];
    const float* W_hc = (const float*)d_in[10];
    const float* b_c  = (const float*)d_in[11];
    const float* W_xo = (const float*)d_in[12];
    const float* W_ho = (const float*)d_in[13];
    const float* b_o  = (const float*)d_in[14];

    const size_t WT_BYTES = (size_t)4 * HID * KTOT * sizeof(uint16_t); // 64 MiB
    const size_t XH_BYTES = (size_t)BATCH * KTOT * sizeof(uint16_t);   // 32 MiB

    if (ws_size >= WT_BYTES + XH_BYTES) {
        uint16_t* wt = (uint16_t*)d_ws;
        uint16_t* xh = (uint16_t*)((char*)d_ws + WT_BYTES);
        // gate order i,f,o,c
        hipLaunchKernelGGL(conv_w, dim3(8 * 256), dim3(256), 0, stream,
                           W_xi, W_hi, W_xf, W_hf, W_xo, W_ho, W_xc, W_hc, wt);
        hipLaunchKernelGGL(conv_a, dim3((BATCH * KTOT) / (256 * 8)), dim3(256), 0, stream,
                           x, h_x, xh);
        hipLaunchKernelGGL(lstm_gemm_bf16, dim3((BATCH / 256) * (HID / 64)), dim3(512), 0, stream,
                           xh, c_x, wt, b_i, b_f, b_o, b_c, (float*)d_out);
    } else {
        hipLaunchKernelGGL(lstm_fused_f32, dim3(HID / 32, BATCH / 128), dim3(256), 0, stream,
                           x, h_x, c_x,
                           W_xi, W_hi, W_xf, W_hf, W_xo, W_ho, W_xc, W_hc,
                           b_i, b_f, b_o, b_c, (float*)d_out);
    }
}